// Round 10
// baseline (216.058 us; speedup 1.0000x reference)
//
#include <hip/hip_runtime.h>
#include <math.h>

#define N_NODES 40000
#define N_EDGES 640000
#define D 128
#define H 8
#define C 16
#define NBG 1250     // 40000/32 exactly
#define KP 136       // sA k-stride (bf16 elems)
#define NBUCK 2500   // 16-node buckets: bucket = dst >> 4 (40000 = 2500*16)
#define NCH 512      // chunks (1250 edges each) — 512 count blocks, 2/CU
#define ECH 1250     // edges per chunk (512*1250 = 640000)
#define CAP 4        // per-(bucket,chunk) slots (32-B cell); lambda=0.5,
                     // P(overflow per cell) ~1.6e-4 -> ~210 edges to ovf list
#define SLOTS_B (NCH * CAP)   // 2048 slots (16 KB) per bucket
#define MAXB 384     // bucket-size bound (mean 256, sigma 16; 8-sigma guard)
#define OVCAP 4096   // global overflow list capacity
#define SOVC 64      // per-block overflow staging

typedef __attribute__((ext_vector_type(8))) short short8;   // 8 bf16 (4 VGPRs)
typedef __attribute__((ext_vector_type(4))) float floatx4;  // MFMA C/D

// ws layout (float offsets):
//  xh    : 0          .. 2,560,000   (N*128 bf16 stored as ushort)
//  al    : 5,120,000  .. 5,440,000   (N*8)
//  ar    : 5,440,000  .. 5,760,000   (N*8)
//  einfo : 6,000,000  .. 16,240,000  (NBUCK*SLOTS_B uint2 fixed cells;
//                                     einfo[(b*512+c)*4+r]={(src<<4)|dl, ew})
//  cnt2  : 16,300,000 .. 17,580,000  ([512][2500] ints, raw per-cell counts)
//  ovfn  : 17,600,000 (1 int)  ovf: 17,600,064 .. +4*OVCAP (uint4 entries)
//  wt    : 17,700,000 .. +16,384     (2x 128x128 bf16 transposed weights)

__device__ __forceinline__ unsigned short f2bf(float f) {
  const unsigned u = __float_as_uint(f);
  return (unsigned short)((u + 0x7FFFu + ((u >> 16) & 1u)) >> 16);  // RNE
}
__device__ __forceinline__ float bflo(unsigned p) {
  return __uint_as_float(p << 16);
}
__device__ __forceinline__ float bfhi(unsigned p) {
  return __uint_as_float(p & 0xFFFF0000u);
}
__device__ __forceinline__ float bf2f(unsigned short u) {
  return __uint_as_float((unsigned)u << 16);
}

// Pre-transpose W (fp32 [k][n]) -> wt (bf16 [g][n][k]). Also zeroes the
// overflow counter (runs before k_gemm in-stream).
__global__ void k_prep(const float* __restrict__ Wlin,
                       const float* __restrict__ Wres,
                       unsigned short* __restrict__ wt, int* __restrict__ ovfn)
{
  const int n = blockIdx.x, k = threadIdx.x, g = blockIdx.y;
  if (n == 0 && g == 0 && k == 0) *ovfn = 0;
  const float* W = g ? Wres : Wlin;
  wt[((g * 128 + n) * 128) + k] = f2bf(W[(long)k * 128 + n]);
}

// MFMA bf16 GEMM, 32-row blocks, BOTH weight matrices per block.
// blockIdx.y==0: xh=bf16(feat@Wlin) + fused alpha epilogue, outp=feat@Wres.
// blockIdx.y==1: count pass (512 blocks x 1250 edges — round-7-proven
//   parallelism) scattering einfo into fixed 32-B cells:
//   slot=(b*512+c)*4 + r (r = LDS rank). Rare r>=4 -> global overflow list.
__global__ __launch_bounds__(256, 4) void k_gemm(
    const float* __restrict__ feat, const unsigned short* __restrict__ wt,
    unsigned short* __restrict__ xh, float* __restrict__ outp,
    const float* __restrict__ attl, const float* __restrict__ attr,
    float* __restrict__ al, float* __restrict__ ar,
    const int* __restrict__ src, const int* __restrict__ dst,
    const float* __restrict__ ew, uint2* __restrict__ einfo,
    int* __restrict__ cnt2, int* __restrict__ ovfn, uint4* __restrict__ ovf)
{
  __shared__ short sA[32 * KP];     // 8,704 B
  __shared__ float sD[32 * 132];    // 16,896 B
  const int t = threadIdx.x;

  if (blockIdx.y == 1) {            // fused count + direct-scatter pass
    if (blockIdx.x >= NCH) return;
    int* lcnt = (int*)sD;           // 10,000 B (2500 bins)
    for (int i = t; i < NBUCK; i += 256) lcnt[i] = 0;
    __syncthreads();
    const int c = blockIdx.x;
    const int e0 = c * ECH;
    for (int e = e0 + t; e < e0 + ECH; e += 256) {
      const int d = dst[e];
      const int b = d >> 4, dl = d & 15;
      const int r = atomicAdd(&lcnt[b], 1);   // LDS atomic only
      const unsigned pay = ((unsigned)src[e] << 4) | (unsigned)dl;
      const unsigned wbits = __float_as_uint(ew[e]);
      if (r < CAP) {
        einfo[((long)b * NCH + c) * CAP + r] = make_uint2(pay, wbits);
      } else {                                 // ~210 expected edges total
        const int oi = atomicAdd(ovfn, 1);
        if (oi < OVCAP)
          ovf[oi] = make_uint4((unsigned)b, (unsigned)dl,
                               (unsigned)src[e], wbits);
      }
    }
    __syncthreads();
    for (int i = t; i < NBUCK; i += 256) cnt2[c * NBUCK + i] = lcnt[i];
    return;
  }

  const int row0 = blockIdx.x * 32;

  // stage A: 32 rows x 128 k, fp32 -> bf16 (coalesced float4 reads)
  {
    const int kq = t & 31;            // k = kq*4
    const int rb = (t >> 5) * 4;      // 4 rows per thread
    #pragma unroll
    for (int i = 0; i < 4; ++i) {
      const int r = rb + i;
      const float4 f = *(const float4*)&feat[(long)(row0 + r) * 128 + kq * 4];
      const unsigned lo = (unsigned)f2bf(f.x) | ((unsigned)f2bf(f.y) << 16);
      const unsigned hi = (unsigned)f2bf(f.z) | ((unsigned)f2bf(f.w) << 16);
      *(uint2*)&sA[r * KP + kq * 4] = make_uint2(lo, hi);
    }
  }

  const int w = t >> 6, lane = t & 63;
  const int c15 = lane & 15, q = lane >> 4;

  // B frags for both weight matrices: wave w owns n-tiles {2w, 2w+1}
  short8 bfr0[4][2], bfr1[4][2];
  #pragma unroll
  for (int kc = 0; kc < 4; ++kc)
    #pragma unroll
    for (int nt = 0; nt < 2; ++nt) {
      const int n = (w * 2 + nt) * 16 + c15;
      bfr0[kc][nt] = *(const short8*)&wt[n * 128 + kc * 32 + q * 8];
      bfr1[kc][nt] = *(const short8*)&wt[16384 + n * 128 + kc * 32 + q * 8];
    }
  __syncthreads();

  floatx4 acc0[2][2], acc1[2][2];
  #pragma unroll
  for (int mt = 0; mt < 2; ++mt)
    #pragma unroll
    for (int nt = 0; nt < 2; ++nt) {
      acc0[mt][nt] = (floatx4){0.f, 0.f, 0.f, 0.f};
      acc1[mt][nt] = (floatx4){0.f, 0.f, 0.f, 0.f};
    }
  #pragma unroll
  for (int kc = 0; kc < 4; ++kc)
    #pragma unroll
    for (int mt = 0; mt < 2; ++mt) {
      const short8 afr = *(const short8*)&sA[(mt * 16 + c15) * KP + kc * 32 + q * 8];
      acc0[mt][0] = __builtin_amdgcn_mfma_f32_16x16x32_bf16(afr, bfr0[kc][0], acc0[mt][0], 0, 0, 0);
      acc0[mt][1] = __builtin_amdgcn_mfma_f32_16x16x32_bf16(afr, bfr0[kc][1], acc0[mt][1], 0, 0, 0);
      acc1[mt][0] = __builtin_amdgcn_mfma_f32_16x16x32_bf16(afr, bfr1[kc][0], acc1[mt][0], 0, 0, 0);
      acc1[mt][1] = __builtin_amdgcn_mfma_f32_16x16x32_bf16(afr, bfr1[kc][1], acc1[mt][1], 0, 0, 0);
    }

  const int orow = t >> 3, seg = t & 7;
  const int grow = row0 + orow;

  // ---- pass 0: xh + alpha from acc0 ----
  #pragma unroll
  for (int mt = 0; mt < 2; ++mt)
    #pragma unroll
    for (int nt = 0; nt < 2; ++nt) {
      const int col = (w * 2 + nt) * 16 + c15;
      #pragma unroll
      for (int r = 0; r < 4; ++r)
        sD[(mt * 16 + q * 4 + r) * 132 + col] = acc0[mt][nt][r];
    }
  __syncthreads();
  {
    #pragma unroll
    for (int i = 0; i < 2; ++i) {     // 8 cols per iter
      const float4 v0 = *(const float4*)&sD[orow * 132 + seg * 16 + i * 8];
      const float4 v1 = *(const float4*)&sD[orow * 132 + seg * 16 + i * 8 + 4];
      uint4 u;
      u.x = (unsigned)f2bf(v0.x) | ((unsigned)f2bf(v0.y) << 16);
      u.y = (unsigned)f2bf(v0.z) | ((unsigned)f2bf(v0.w) << 16);
      u.z = (unsigned)f2bf(v1.x) | ((unsigned)f2bf(v1.y) << 16);
      u.w = (unsigned)f2bf(v1.z) | ((unsigned)f2bf(v1.w) << 16);
      *(uint4*)&xh[(long)grow * 128 + seg * 16 + i * 8] = u;
    }
    // fused alpha epilogue: thread = (node orow, head seg); one 16-dot each.
    const int h = seg;
    float sl = 0.f, sr = 0.f;
    #pragma unroll
    for (int c4 = 0; c4 < 4; ++c4) {
      const float4 xv = *(const float4*)&sD[orow * 132 + h * 16 + c4 * 4];
      const float4 lv = *(const float4*)&attl[h * 16 + c4 * 4];
      const float4 rv = *(const float4*)&attr[h * 16 + c4 * 4];
      sl += xv.x * lv.x + xv.y * lv.y + xv.z * lv.z + xv.w * lv.w;
      sr += xv.x * rv.x + xv.y * rv.y + xv.z * rv.z + xv.w * rv.w;
    }
    al[(long)grow * 8 + h] = sl;
    ar[(long)grow * 8 + h] = sr;
  }
  __syncthreads();

  // ---- pass 1: outp from acc1 ----
  #pragma unroll
  for (int mt = 0; mt < 2; ++mt)
    #pragma unroll
    for (int nt = 0; nt < 2; ++nt) {
      const int col = (w * 2 + nt) * 16 + c15;
      #pragma unroll
      for (int r = 0; r < 4; ++r)
        sD[(mt * 16 + q * 4 + r) * 132 + col] = acc1[mt][nt][r];
    }
  __syncthreads();
  #pragma unroll
  for (int i = 0; i < 4; ++i) {
    const float4 v = *(const float4*)&sD[orow * 132 + seg * 16 + i * 4];
    *(float4*)&outp[(long)grow * 128 + seg * 16 + i * 4] = v;
  }
}

// FUSED edge+aggregate, SINGLE-SWEEP UNSORTED: one 256-thread block per
// 16-node bucket (2500 blocks, 4 waves, ~11 KB LDS -> 8 blocks/CU).
//  sweep (once): coalesced 16-KB slot-window read; for valid slots compute
//    exp(logits) (al gathered L2-hot, ar in LDS) and append {(dl<<16)|src,
//    pexp[8]} to an UNSORTED LDS list via one cursor. No counting sort, no
//    second sweep — halves einfo HBM traffic vs round 9.
//  phase 4: wave wv scans the LDS list (broadcast reads, wave-uniform dl
//    test -> cheap skip) and accumulates its 4 nodes in statically-named
//    register accumulators (wave-uniform 4-way branch; no dynamic indexing).
// pexp: no max subtraction (logits bounded ~|4|, softmax shift-invariant —
// validated in earlier rounds).
__global__ __launch_bounds__(256, 8) void k_edgeagg(
    const int* __restrict__ cnt2, const uint2* __restrict__ einfo,
    const int* __restrict__ ovfn, const uint4* __restrict__ ovf,
    const float* __restrict__ al, const float* __restrict__ ar,
    const unsigned short* __restrict__ xh, float* __restrict__ outp)
{
  __shared__ unsigned short sP[MAXB * 8];  // 6,144 B (pexp, bf16, unsorted)
  __shared__ int sS[MAXB];                 // 1,536 B ((dl<<16)|src)
  __shared__ float sAr[128];               //   512 B (16 nodes x 8 heads)
  __shared__ int scnt[NCH];                // 2,048 B (clamped counts)
  __shared__ int nE;
  const int b = blockIdx.x;
  const int t = threadIdx.x;
  if (t == 0) nE = 0;
  if (t < 128) sAr[t] = ar[(long)(b << 4) * 8 + t];
  for (int i = t; i < NCH; i += 256)
    scnt[i] = min(cnt2[i * NBUCK + b], CAP);
  __syncthreads();

  const long base = (long)b * SLOTS_B;

  // single sweep: exp + unsorted append
  auto process = [&](unsigned pay, unsigned wbits) {
    const int dl = pay & 15;
    const int s = (int)(pay >> 4);
    const float w = __uint_as_float(wbits);
    const float4 l0 = *(const float4*)&al[(long)s * 8];
    const float4 l1 = *(const float4*)&al[(long)s * 8 + 4];
    const float* arr = &sAr[dl * 8];
    float lv[8] = {l0.x + arr[0], l0.y + arr[1], l0.z + arr[2], l0.w + arr[3],
                   l1.x + arr[4], l1.y + arr[5], l1.z + arr[6], l1.w + arr[7]};
    #pragma unroll
    for (int h = 0; h < 8; ++h) {
      float a = w * lv[h];
      a = (a >= 0.f) ? a : 0.2f * a;   // leaky_relu(0.2)
      lv[h] = __expf(a);
    }
    const int k = atomicAdd(&nE, 1);     // LDS atomic, ~256/block
    if (k < MAXB) {
      sS[k] = (dl << 16) | s;
      uint4 u;
      u.x = (unsigned)f2bf(lv[0]) | ((unsigned)f2bf(lv[1]) << 16);
      u.y = (unsigned)f2bf(lv[2]) | ((unsigned)f2bf(lv[3]) << 16);
      u.z = (unsigned)f2bf(lv[4]) | ((unsigned)f2bf(lv[5]) << 16);
      u.w = (unsigned)f2bf(lv[6]) | ((unsigned)f2bf(lv[7]) << 16);
      *(uint4*)&sP[k * 8] = u;
    }
  };
  for (int i = t; i < SLOTS_B; i += 256) {
    const int c = i >> 2, r = i & 3;
    if (r < scnt[c]) {
      const uint2 m = einfo[base + i];
      process(m.x, m.y);
    }
  }
  const int no = *ovfn;                    // ~210 chip-wide, list L2-hot
  for (int i = t; i < no; i += 256) {
    const uint4 o = ovf[i];
    if ((int)o.x == b) process((o.z << 4) | o.y, o.w);
  }
  __syncthreads();

  // phase 4: unsorted aggregation. wave wv owns nodes wv*4 .. wv*4+3.
  const int wv = t >> 6, lane = t & 63;
  const int h = lane >> 3;
  const int co = lane * 2;
  const int nEv = min(nE, MAXB);

  float2 aA = {0.f, 0.f}, aB = {0.f, 0.f}, aC = {0.f, 0.f}, aD = {0.f, 0.f};
  float ssA = 0.f, ssB = 0.f, ssC = 0.f, ssD = 0.f;
  for (int p = 0; p < nEv; ++p) {
    const int rec = sS[p];                 // LDS broadcast (uniform addr)
    const int dl = rec >> 16;
    if ((dl >> 2) != wv) continue;         // wave-uniform skip
    const int s = rec & 0xFFFF;
    const float ev = bf2f(sP[p * 8 + h]);
    const unsigned v = *(const unsigned*)&xh[(long)s * 128 + co];
    const float xl = bflo(v), xhv = bfhi(v);
    const int j = dl & 3;                  // wave-uniform
    if (j == 0)      { aA.x = fmaf(xl, ev, aA.x); aA.y = fmaf(xhv, ev, aA.y); ssA += ev; }
    else if (j == 1) { aB.x = fmaf(xl, ev, aB.x); aB.y = fmaf(xhv, ev, aB.y); ssB += ev; }
    else if (j == 2) { aC.x = fmaf(xl, ev, aC.x); aC.y = fmaf(xhv, ev, aC.y); ssC += ev; }
    else             { aD.x = fmaf(xl, ev, aD.x); aD.y = fmaf(xhv, ev, aD.y); ssD += ev; }
  }

  auto wout = [&](int j, float2 a, float ss) {
    if (ss <= 0.f) return;                 // empty node keeps residual
    const float rs = 1.0f / ss;
    const float ax = a.x * rs, ay = a.y * rs;
    const long dnode = (long)(b << 4) + wv * 4 + j;
    float2 o = *(float2*)&outp[dnode * 128 + co];
    o.x += (ax > 0.f) ? ax : expm1f(ax);
    o.y += (ay > 0.f) ? ay : expm1f(ay);
    *(float2*)&outp[dnode * 128 + co] = o;
  };
  wout(0, aA, ssA);
  wout(1, aB, ssB);
  wout(2, aC, ssC);
  wout(3, aD, ssD);
}

extern "C" void kernel_launch(void* const* d_in, const int* in_sizes, int n_in,
                              void* d_out, int out_size, void* d_ws, size_t ws_size,
                              hipStream_t stream) {
  const float* feat = (const float*)d_in[0];
  const int*   eidx = (const int*)d_in[1];
  const float* ew   = (const float*)d_in[2];
  const float* Wlin = (const float*)d_in[3];
  const float* attl = (const float*)d_in[4];
  const float* attr = (const float*)d_in[5];
  const float* Wres = (const float*)d_in[6];
  float* outp = (float*)d_out;

  float* ws = (float*)d_ws;
  unsigned short* xh = (unsigned short*)ws;
  float* al   = ws + 5120000;
  float* ar   = ws + 5440000;
  uint2* einfo = (uint2*)(ws + 6000000);   // NBUCK*SLOTS_B uint2 (40.9 MB)
  int*   cnt2 = (int*)(ws + 16300000);
  int*   ovfn = (int*)(ws + 17600000);
  uint4* ovf  = (uint4*)(ws + 17600064);
  unsigned short* wt = (unsigned short*)(ws + 17700000);

  const int* src = eidx;
  const int* dst = eidx + N_EDGES;

  dim3 pgrid(128, 2);
  k_prep<<<pgrid, 128, 0, stream>>>(Wlin, Wres, wt, ovfn);
  dim3 ggrid(NBG, 2);   // y=0 dual GEMM + alpha, y=1 count + direct scatter
  k_gemm<<<ggrid, 256, 0, stream>>>(feat, wt, xh, outp, attl, attr, al, ar,
                                    src, dst, ew, einfo, cnt2, ovfn, ovf);
  k_edgeagg<<<NBUCK, 256, 0, stream>>>(cnt2, einfo, ovfn, ovf, al, ar,
                                       xh, outp);
}

// Round 11
// 164.947 us; speedup vs baseline: 1.3099x; 1.3099x over previous
//
#include <hip/hip_runtime.h>
#include <math.h>

#define N_NODES 40000
#define N_EDGES 640000
#define D 128
#define H 8
#define C 16
#define NBG 1250     // 40000/32 exactly
#define KP 136       // sA k-stride (bf16 elems)
#define NBUCK 2500   // 16-node buckets: bucket = dst >> 4 (40000 = 2500*16)
#define NCH 512      // chunks (1250 edges each) — 512 count blocks, 2/CU
#define ECH 1250     // edges per chunk (512*1250 = 640000)
#define CAP 4        // per-(bucket,chunk) slots (32-B cell); lambda=0.5,
                     // P(overflow per cell) ~1.6e-4 -> ~210 edges to ovf list
#define SLOTS_B (NCH * CAP)   // 2048 slots (16 KB) per bucket
#define MAXB 384     // bucket-size bound (mean 256, sigma 16; 8-sigma guard)
#define OVCAP 4096   // global overflow list capacity

typedef __attribute__((ext_vector_type(8))) short short8;   // 8 bf16 (4 VGPRs)
typedef __attribute__((ext_vector_type(4))) float floatx4;  // MFMA C/D

// ws layout (float offsets):
//  xh    : 0          .. 2,560,000   (N*128 bf16 stored as ushort)
//  al    : 5,120,000  .. 5,440,000   (N*8)
//  ar    : 5,440,000  .. 5,760,000   (N*8)
//  einfo : 6,000,000  .. 16,240,000  (NBUCK*SLOTS_B uint2 fixed cells;
//                                     einfo[(b*512+c)*4+r]={(src<<4)|dl, ew})
//  cnt2  : 16,300,000 .. 17,580,000  ([512][2500] ints, raw per-cell counts)
//  ovfn  : 17,600,000 (1 int)  ovf: 17,600,064 .. +4*OVCAP (uint4 entries)
//  wt    : 17,700,000 .. +16,384     (2x 128x128 bf16 transposed weights)

__device__ __forceinline__ unsigned short f2bf(float f) {
  const unsigned u = __float_as_uint(f);
  return (unsigned short)((u + 0x7FFFu + ((u >> 16) & 1u)) >> 16);  // RNE
}
__device__ __forceinline__ float bflo(unsigned p) {
  return __uint_as_float(p << 16);
}
__device__ __forceinline__ float bfhi(unsigned p) {
  return __uint_as_float(p & 0xFFFF0000u);
}
__device__ __forceinline__ float bf2f(unsigned short u) {
  return __uint_as_float((unsigned)u << 16);
}

// Pre-transpose W (fp32 [k][n]) -> wt (bf16 [g][n][k]). Also zeroes the
// overflow counter (runs before k_gemm in-stream).
__global__ void k_prep(const float* __restrict__ Wlin,
                       const float* __restrict__ Wres,
                       unsigned short* __restrict__ wt, int* __restrict__ ovfn)
{
  const int n = blockIdx.x, k = threadIdx.x, g = blockIdx.y;
  if (n == 0 && g == 0 && k == 0) *ovfn = 0;
  const float* W = g ? Wres : Wlin;
  wt[((g * 128 + n) * 128) + k] = f2bf(W[(long)k * 128 + n]);
}

// MFMA bf16 GEMM, 32-row blocks, BOTH weight matrices per block.
// blockIdx.y==0: xh=bf16(feat@Wlin) + fused alpha epilogue, outp=feat@Wres.
// blockIdx.y==1: count pass (512 blocks x 1250 edges — round-7/9-proven
//   parallelism) scattering einfo into fixed 32-B cells:
//   slot=(b*512+c)*4 + r (r = LDS rank). Rare r>=4 -> global overflow list.
__global__ __launch_bounds__(256, 4) void k_gemm(
    const float* __restrict__ feat, const unsigned short* __restrict__ wt,
    unsigned short* __restrict__ xh, float* __restrict__ outp,
    const float* __restrict__ attl, const float* __restrict__ attr,
    float* __restrict__ al, float* __restrict__ ar,
    const int* __restrict__ src, const int* __restrict__ dst,
    const float* __restrict__ ew, uint2* __restrict__ einfo,
    int* __restrict__ cnt2, int* __restrict__ ovfn, uint4* __restrict__ ovf)
{
  __shared__ short sA[32 * KP];     // 8,704 B
  __shared__ float sD[32 * 132];    // 16,896 B
  const int t = threadIdx.x;

  if (blockIdx.y == 1) {            // fused count + direct-scatter pass
    if (blockIdx.x >= NCH) return;
    int* lcnt = (int*)sD;           // 10,000 B (2500 bins)
    for (int i = t; i < NBUCK; i += 256) lcnt[i] = 0;
    __syncthreads();
    const int c = blockIdx.x;
    const int e0 = c * ECH;
    for (int e = e0 + t; e < e0 + ECH; e += 256) {
      const int d = dst[e];
      const int b = d >> 4, dl = d & 15;
      const int r = atomicAdd(&lcnt[b], 1);   // LDS atomic only
      const unsigned pay = ((unsigned)src[e] << 4) | (unsigned)dl;
      const unsigned wbits = __float_as_uint(ew[e]);
      if (r < CAP) {
        einfo[((long)b * NCH + c) * CAP + r] = make_uint2(pay, wbits);
      } else {                                 // ~210 expected edges total
        const int oi = atomicAdd(ovfn, 1);
        if (oi < OVCAP)
          ovf[oi] = make_uint4((unsigned)b, (unsigned)dl,
                               (unsigned)src[e], wbits);
      }
    }
    __syncthreads();
    for (int i = t; i < NBUCK; i += 256) cnt2[c * NBUCK + i] = lcnt[i];
    return;
  }

  const int row0 = blockIdx.x * 32;

  // stage A: 32 rows x 128 k, fp32 -> bf16 (coalesced float4 reads)
  {
    const int kq = t & 31;            // k = kq*4
    const int rb = (t >> 5) * 4;      // 4 rows per thread
    #pragma unroll
    for (int i = 0; i < 4; ++i) {
      const int r = rb + i;
      const float4 f = *(const float4*)&feat[(long)(row0 + r) * 128 + kq * 4];
      const unsigned lo = (unsigned)f2bf(f.x) | ((unsigned)f2bf(f.y) << 16);
      const unsigned hi = (unsigned)f2bf(f.z) | ((unsigned)f2bf(f.w) << 16);
      *(uint2*)&sA[r * KP + kq * 4] = make_uint2(lo, hi);
    }
  }

  const int w = t >> 6, lane = t & 63;
  const int c15 = lane & 15, q = lane >> 4;

  // B frags for both weight matrices: wave w owns n-tiles {2w, 2w+1}
  short8 bfr0[4][2], bfr1[4][2];
  #pragma unroll
  for (int kc = 0; kc < 4; ++kc)
    #pragma unroll
    for (int nt = 0; nt < 2; ++nt) {
      const int n = (w * 2 + nt) * 16 + c15;
      bfr0[kc][nt] = *(const short8*)&wt[n * 128 + kc * 32 + q * 8];
      bfr1[kc][nt] = *(const short8*)&wt[16384 + n * 128 + kc * 32 + q * 8];
    }
  __syncthreads();

  floatx4 acc0[2][2], acc1[2][2];
  #pragma unroll
  for (int mt = 0; mt < 2; ++mt)
    #pragma unroll
    for (int nt = 0; nt < 2; ++nt) {
      acc0[mt][nt] = (floatx4){0.f, 0.f, 0.f, 0.f};
      acc1[mt][nt] = (floatx4){0.f, 0.f, 0.f, 0.f};
    }
  #pragma unroll
  for (int kc = 0; kc < 4; ++kc)
    #pragma unroll
    for (int mt = 0; mt < 2; ++mt) {
      const short8 afr = *(const short8*)&sA[(mt * 16 + c15) * KP + kc * 32 + q * 8];
      acc0[mt][0] = __builtin_amdgcn_mfma_f32_16x16x32_bf16(afr, bfr0[kc][0], acc0[mt][0], 0, 0, 0);
      acc0[mt][1] = __builtin_amdgcn_mfma_f32_16x16x32_bf16(afr, bfr0[kc][1], acc0[mt][1], 0, 0, 0);
      acc1[mt][0] = __builtin_amdgcn_mfma_f32_16x16x32_bf16(afr, bfr1[kc][0], acc1[mt][0], 0, 0, 0);
      acc1[mt][1] = __builtin_amdgcn_mfma_f32_16x16x32_bf16(afr, bfr1[kc][1], acc1[mt][1], 0, 0, 0);
    }

  const int orow = t >> 3, seg = t & 7;
  const int grow = row0 + orow;

  // ---- pass 0: xh + alpha from acc0 ----
  #pragma unroll
  for (int mt = 0; mt < 2; ++mt)
    #pragma unroll
    for (int nt = 0; nt < 2; ++nt) {
      const int col = (w * 2 + nt) * 16 + c15;
      #pragma unroll
      for (int r = 0; r < 4; ++r)
        sD[(mt * 16 + q * 4 + r) * 132 + col] = acc0[mt][nt][r];
    }
  __syncthreads();
  {
    #pragma unroll
    for (int i = 0; i < 2; ++i) {     // 8 cols per iter
      const float4 v0 = *(const float4*)&sD[orow * 132 + seg * 16 + i * 8];
      const float4 v1 = *(const float4*)&sD[orow * 132 + seg * 16 + i * 8 + 4];
      uint4 u;
      u.x = (unsigned)f2bf(v0.x) | ((unsigned)f2bf(v0.y) << 16);
      u.y = (unsigned)f2bf(v0.z) | ((unsigned)f2bf(v0.w) << 16);
      u.z = (unsigned)f2bf(v1.x) | ((unsigned)f2bf(v1.y) << 16);
      u.w = (unsigned)f2bf(v1.z) | ((unsigned)f2bf(v1.w) << 16);
      *(uint4*)&xh[(long)grow * 128 + seg * 16 + i * 8] = u;
    }
    // fused alpha epilogue: thread = (node orow, head seg); one 16-dot each.
    const int h = seg;
    float sl = 0.f, sr = 0.f;
    #pragma unroll
    for (int c4 = 0; c4 < 4; ++c4) {
      const float4 xv = *(const float4*)&sD[orow * 132 + h * 16 + c4 * 4];
      const float4 lv = *(const float4*)&attl[h * 16 + c4 * 4];
      const float4 rv = *(const float4*)&attr[h * 16 + c4 * 4];
      sl += xv.x * lv.x + xv.y * lv.y + xv.z * lv.z + xv.w * lv.w;
      sr += xv.x * rv.x + xv.y * rv.y + xv.z * rv.z + xv.w * rv.w;
    }
    al[(long)grow * 8 + h] = sl;
    ar[(long)grow * 8 + h] = sr;
  }
  __syncthreads();

  // ---- pass 1: outp from acc1 ----
  #pragma unroll
  for (int mt = 0; mt < 2; ++mt)
    #pragma unroll
    for (int nt = 0; nt < 2; ++nt) {
      const int col = (w * 2 + nt) * 16 + c15;
      #pragma unroll
      for (int r = 0; r < 4; ++r)
        sD[(mt * 16 + q * 4 + r) * 132 + col] = acc1[mt][nt][r];
    }
  __syncthreads();
  #pragma unroll
  for (int i = 0; i < 4; ++i) {
    const float4 v = *(const float4*)&sD[orow * 132 + seg * 16 + i * 4];
    *(float4*)&outp[(long)grow * 128 + seg * 16 + i * 4] = v;
  }
}

// FUSED edge+aggregate: one 256-thread block per 16-node bucket (2500 blocks,
// 4 waves, ~13.5 KB LDS -> 8 blocks/CU). SINGLE global sweep + LDS sort:
//  sweep (once): coalesced 16-KB slot-window read; valid slots appended raw
//    to sE (unsorted, one LDS cursor) + 16-bin count. Halves R9's global
//    slot traffic (one sweep, not two).
//  scan: lanes 0-15 shuffle scan of bins.
//  sort (LDS-local): read sE, compute exp(logits) (al gathered L2-hot, ar in
//    LDS), counting-sort into sP/sS — contiguous per-node runs.
//  phase 4: sorted per-node register aggregation with 4-edge ILP
//    (round-8-proven): wave wv owns 4 nodes; acc += pexp*x; normalize, ELU,
//    residual RMW. NOT the round-10 serial unsorted scan (120 us lesson).
// pexp: no max subtraction (logits bounded ~|4|, softmax shift-invariant —
// validated in earlier rounds).
__global__ __launch_bounds__(256, 8) void k_edgeagg(
    const int* __restrict__ cnt2, const uint2* __restrict__ einfo,
    const int* __restrict__ ovfn, const uint4* __restrict__ ovf,
    const float* __restrict__ al, const float* __restrict__ ar,
    const unsigned short* __restrict__ xh, float* __restrict__ outp)
{
  __shared__ uint2 sE[MAXB];               // 3,072 B (raw slots, unsorted)
  __shared__ unsigned short sP[MAXB * 8];  // 6,144 B (sorted pexp, bf16)
  __shared__ int sS[MAXB];                 // 1,536 B (sorted src ids)
  __shared__ float sAr[128];               //   512 B (16 nodes x 8 heads)
  __shared__ int scnt[NCH];                // 2,048 B (clamped counts)
  __shared__ int bcnt[16], bbase[16], bpos[16], nE;
  const int b = blockIdx.x;
  const int t = threadIdx.x;
  if (t < 16) bcnt[t] = 0;
  if (t == 16) nE = 0;
  if (t < 128) sAr[t] = ar[(long)(b << 4) * 8 + t];
  for (int i = t; i < NCH; i += 256)
    scnt[i] = min(cnt2[i * NBUCK + b], CAP);
  __syncthreads();

  const long base = (long)b * SLOTS_B;

  // single global sweep: raw append + bin count
  for (int i = t; i < SLOTS_B; i += 256) {
    const int c = i >> 2, r = i & 3;
    if (r < scnt[c]) {
      const uint2 m = einfo[base + i];
      const int k = atomicAdd(&nE, 1);     // LDS atomic only
      if (k < MAXB) {
        sE[k] = m;
        atomicAdd(&bcnt[m.x & 15], 1);
      }
    }
  }
  const int no = *ovfn;                    // ~210 chip-wide, list L2-hot
  for (int i = t; i < no; i += 256) {
    const uint4 o = ovf[i];
    if ((int)o.x == b) {
      const int k = atomicAdd(&nE, 1);
      if (k < MAXB) {
        sE[k] = make_uint2((o.z << 4) | o.y, o.w);
        atomicAdd(&bcnt[o.y], 1);
      }
    }
  }
  __syncthreads();
  const int nEv = min(nE, MAXB);

  if (t < 16) {            // scan of 16 bins (lanes 0-15, wave 0)
    const int v = bcnt[t];
    int incl = v;
    #pragma unroll
    for (int off = 1; off < 16; off <<= 1) {
      const int n = __shfl_up(incl, off, 16);
      if (t >= off) incl += n;
    }
    bbase[t] = incl - v;
    bpos[t] = 0;
  }
  __syncthreads();

  // LDS-local sort pass: exp + counting sort into sP/sS
  for (int i = t; i < nEv; i += 256) {
    const uint2 m = sE[i];
    const int dl = m.x & 15;
    const int s = (int)(m.x >> 4);
    const float w = __uint_as_float(m.y);
    const float4 l0 = *(const float4*)&al[(long)s * 8];
    const float4 l1 = *(const float4*)&al[(long)s * 8 + 4];
    const float* arr = &sAr[dl * 8];
    float lv[8] = {l0.x + arr[0], l0.y + arr[1], l0.z + arr[2], l0.w + arr[3],
                   l1.x + arr[4], l1.y + arr[5], l1.z + arr[6], l1.w + arr[7]};
    #pragma unroll
    for (int h = 0; h < 8; ++h) {
      float a = w * lv[h];
      a = (a >= 0.f) ? a : 0.2f * a;   // leaky_relu(0.2)
      lv[h] = __expf(a);
    }
    const int r = atomicAdd(&bpos[dl], 1);   // LDS atomic only
    const int qq = bbase[dl] + r;
    sS[qq] = s;
    uint4 u;
    u.x = (unsigned)f2bf(lv[0]) | ((unsigned)f2bf(lv[1]) << 16);
    u.y = (unsigned)f2bf(lv[2]) | ((unsigned)f2bf(lv[3]) << 16);
    u.z = (unsigned)f2bf(lv[4]) | ((unsigned)f2bf(lv[5]) << 16);
    u.w = (unsigned)f2bf(lv[6]) | ((unsigned)f2bf(lv[7]) << 16);
    *(uint4*)&sP[qq * 8] = u;
  }
  __syncthreads();

  // phase 4: sorted aggregation, 4-edge ILP. wave wv owns nodes wv*4..wv*4+3.
  const int wv = t >> 6, lane = t & 63;
  const int h = lane >> 3;
  const int co = lane * 2;
  #pragma unroll
  for (int j = 0; j < 4; ++j) {
    const int dl = wv * 4 + j;
    const int start = bbase[dl];
    const int end = start + bcnt[dl];
    if (end <= start) continue;   // out already holds residual; elu(0)=0

    float2 a0 = {0.f, 0.f}, a1 = {0.f, 0.f}, a2 = {0.f, 0.f}, a3 = {0.f, 0.f};
    float s0s = 0.f, s1s = 0.f, s2s = 0.f, s3s = 0.f;
    int p = start;
    for (; p + 4 <= end; p += 4) {
      const int s0 = sS[p + 0], s1 = sS[p + 1];
      const int s2 = sS[p + 2], s3 = sS[p + 3];
      const float e0v = bf2f(sP[(p + 0) * 8 + h]);
      const float e1v = bf2f(sP[(p + 1) * 8 + h]);
      const float e2v = bf2f(sP[(p + 2) * 8 + h]);
      const float e3v = bf2f(sP[(p + 3) * 8 + h]);
      const unsigned v0 = *(const unsigned*)&xh[(long)s0 * 128 + co];
      const unsigned v1 = *(const unsigned*)&xh[(long)s1 * 128 + co];
      const unsigned v2 = *(const unsigned*)&xh[(long)s2 * 128 + co];
      const unsigned v3 = *(const unsigned*)&xh[(long)s3 * 128 + co];
      a0.x = fmaf(bflo(v0), e0v, a0.x); a0.y = fmaf(bfhi(v0), e0v, a0.y); s0s += e0v;
      a1.x = fmaf(bflo(v1), e1v, a1.x); a1.y = fmaf(bfhi(v1), e1v, a1.y); s1s += e1v;
      a2.x = fmaf(bflo(v2), e2v, a2.x); a2.y = fmaf(bfhi(v2), e2v, a2.y); s2s += e2v;
      a3.x = fmaf(bflo(v3), e3v, a3.x); a3.y = fmaf(bfhi(v3), e3v, a3.y); s3s += e3v;
    }
    for (; p < end; ++p) {
      const int s = sS[p];
      const float ev = bf2f(sP[p * 8 + h]);
      const unsigned v = *(const unsigned*)&xh[(long)s * 128 + co];
      a0.x = fmaf(bflo(v), ev, a0.x);
      a0.y = fmaf(bfhi(v), ev, a0.y);
      s0s += ev;
    }
    const float rs = 1.0f / ((s0s + s1s) + (s2s + s3s));
    const float ax = ((a0.x + a1.x) + (a2.x + a3.x)) * rs;
    const float ay = ((a0.y + a1.y) + (a2.y + a3.y)) * rs;

    const long dnode = (long)(b << 4) + dl;
    float2 o = *(float2*)&outp[dnode * 128 + co];
    o.x += (ax > 0.f) ? ax : expm1f(ax);
    o.y += (ay > 0.f) ? ay : expm1f(ay);
    *(float2*)&outp[dnode * 128 + co] = o;
  }
}

extern "C" void kernel_launch(void* const* d_in, const int* in_sizes, int n_in,
                              void* d_out, int out_size, void* d_ws, size_t ws_size,
                              hipStream_t stream) {
  const float* feat = (const float*)d_in[0];
  const int*   eidx = (const int*)d_in[1];
  const float* ew   = (const float*)d_in[2];
  const float* Wlin = (const float*)d_in[3];
  const float* attl = (const float*)d_in[4];
  const float* attr = (const float*)d_in[5];
  const float* Wres = (const float*)d_in[6];
  float* outp = (float*)d_out;

  float* ws = (float*)d_ws;
  unsigned short* xh = (unsigned short*)ws;
  float* al   = ws + 5120000;
  float* ar   = ws + 5440000;
  uint2* einfo = (uint2*)(ws + 6000000);   // NBUCK*SLOTS_B uint2 (40.9 MB)
  int*   cnt2 = (int*)(ws + 16300000);
  int*   ovfn = (int*)(ws + 17600000);
  uint4* ovf  = (uint4*)(ws + 17600064);
  unsigned short* wt = (unsigned short*)(ws + 17700000);

  const int* src = eidx;
  const int* dst = eidx + N_EDGES;

  dim3 pgrid(128, 2);
  k_prep<<<pgrid, 128, 0, stream>>>(Wlin, Wres, wt, ovfn);
  dim3 ggrid(NBG, 2);   // y=0 dual GEMM + alpha, y=1 count + direct scatter
  k_gemm<<<ggrid, 256, 0, stream>>>(feat, wt, xh, outp, attl, attr, al, ar,
                                    src, dst, ew, einfo, cnt2, ovfn, ovf);
  k_edgeagg<<<NBUCK, 256, 0, stream>>>(cnt2, einfo, ovfn, ovf, al, ar,
                                       xh, outp);
}

// Round 12
// 161.321 us; speedup vs baseline: 1.3393x; 1.0225x over previous
//
#include <hip/hip_runtime.h>
#include <math.h>

#define N_NODES 40000
#define N_EDGES 640000
#define D 128
#define H 8
#define C 16
#define NBG 1250     // 40000/32 exactly
#define KP 136       // sA k-stride (bf16 elems)
#define NBUCK 2500   // 16-node buckets: bucket = dst >> 4 (40000 = 2500*16)
#define NCH 512      // chunks (1250 edges each) — 512 count blocks, 2/CU
#define ECH 1250     // edges per chunk (512*1250 = 640000)
#define CAP 4        // per-(bucket,chunk) slots (32-B cell); lambda=0.5,
                     // P(overflow per cell) ~1.6e-4 -> ~210 edges to ovf list
#define SLOTS_B (NCH * CAP)   // 2048 slots (16 KB) per bucket
#define MAXB 384     // bucket-size bound (mean 256, sigma 16; 8-sigma guard)
#define OVCAP 4096   // global overflow list capacity

typedef __attribute__((ext_vector_type(8))) short short8;   // 8 bf16 (4 VGPRs)
typedef __attribute__((ext_vector_type(4))) float floatx4;  // MFMA C/D

// ws layout (float offsets):
//  xh    : 0          .. 2,560,000   (N*128 bf16 stored as ushort)
//  al    : 5,120,000  .. 5,440,000   (N*8)
//  ar    : 5,440,000  .. 5,760,000   (N*8)
//  einfo : 6,000,000  .. 16,240,000  (NBUCK*SLOTS_B uint2 fixed cells;
//                                     einfo[(b*512+c)*4+r]={(src<<4)|dl, ew})
//  cnt2  : 16,300,000 .. 17,580,000  ([512][2500] ints, chunk-major counts)
//  ovfn  : 17,600,000 (1 int)  ovf: 17,600,064 .. +4*OVCAP (uint4 entries)
//  cnt2T : 17,700,000 .. 18,980,000  ([2500][512] ints, bucket-major counts)
//  wt    : 19,000,000 .. +16,384     (2x 128x128 bf16 transposed weights)

__device__ __forceinline__ unsigned short f2bf(float f) {
  const unsigned u = __float_as_uint(f);
  return (unsigned short)((u + 0x7FFFu + ((u >> 16) & 1u)) >> 16);  // RNE
}
__device__ __forceinline__ float bflo(unsigned p) {
  return __uint_as_float(p << 16);
}
__device__ __forceinline__ float bfhi(unsigned p) {
  return __uint_as_float(p & 0xFFFF0000u);
}

// Pre-transpose W (fp32 [k][n]) -> wt (bf16 [g][n][k]). Also zeroes the
// overflow counter (runs before k_gemm in-stream).
__global__ void k_prep(const float* __restrict__ Wlin,
                       const float* __restrict__ Wres,
                       unsigned short* __restrict__ wt, int* __restrict__ ovfn)
{
  const int n = blockIdx.x, k = threadIdx.x, g = blockIdx.y;
  if (n == 0 && g == 0 && k == 0) *ovfn = 0;
  const float* W = g ? Wres : Wlin;
  wt[((g * 128 + n) * 128) + k] = f2bf(W[(long)k * 128 + n]);
}

// MFMA bf16 GEMM, 32-row blocks, BOTH weight matrices per block.
// blockIdx.y==0: xh=bf16(feat@Wlin) + fused alpha epilogue, outp=feat@Wres.
// blockIdx.y==1: count pass (512 blocks x 1250 edges — round-7/9-proven
//   parallelism) scattering einfo into fixed 32-B cells:
//   slot=(b*512+c)*4 + r (r = LDS rank). Rare r>=4 -> global overflow list.
__global__ __launch_bounds__(256, 4) void k_gemm(
    const float* __restrict__ feat, const unsigned short* __restrict__ wt,
    unsigned short* __restrict__ xh, float* __restrict__ outp,
    const float* __restrict__ attl, const float* __restrict__ attr,
    float* __restrict__ al, float* __restrict__ ar,
    const int* __restrict__ src, const int* __restrict__ dst,
    const float* __restrict__ ew, uint2* __restrict__ einfo,
    int* __restrict__ cnt2, int* __restrict__ ovfn, uint4* __restrict__ ovf)
{
  __shared__ short sA[32 * KP];     // 8,704 B
  __shared__ float sD[32 * 132];    // 16,896 B
  const int t = threadIdx.x;

  if (blockIdx.y == 1) {            // fused count + direct-scatter pass
    if (blockIdx.x >= NCH) return;
    int* lcnt = (int*)sD;           // 10,000 B (2500 bins)
    for (int i = t; i < NBUCK; i += 256) lcnt[i] = 0;
    __syncthreads();
    const int c = blockIdx.x;
    const int e0 = c * ECH;
    for (int e = e0 + t; e < e0 + ECH; e += 256) {
      const int d = dst[e];
      const int b = d >> 4, dl = d & 15;
      const int r = atomicAdd(&lcnt[b], 1);   // LDS atomic only
      const unsigned pay = ((unsigned)src[e] << 4) | (unsigned)dl;
      const unsigned wbits = __float_as_uint(ew[e]);
      if (r < CAP) {
        einfo[((long)b * NCH + c) * CAP + r] = make_uint2(pay, wbits);
      } else {                                 // ~210 expected edges total
        const int oi = atomicAdd(ovfn, 1);
        if (oi < OVCAP)
          ovf[oi] = make_uint4((unsigned)b, (unsigned)dl,
                               (unsigned)src[e], wbits);
      }
    }
    __syncthreads();
    for (int i = t; i < NBUCK; i += 256) cnt2[c * NBUCK + i] = lcnt[i];
    return;
  }

  const int row0 = blockIdx.x * 32;

  // stage A: 32 rows x 128 k, fp32 -> bf16 (coalesced float4 reads)
  {
    const int kq = t & 31;            // k = kq*4
    const int rb = (t >> 5) * 4;      // 4 rows per thread
    #pragma unroll
    for (int i = 0; i < 4; ++i) {
      const int r = rb + i;
      const float4 f = *(const float4*)&feat[(long)(row0 + r) * 128 + kq * 4];
      const unsigned lo = (unsigned)f2bf(f.x) | ((unsigned)f2bf(f.y) << 16);
      const unsigned hi = (unsigned)f2bf(f.z) | ((unsigned)f2bf(f.w) << 16);
      *(uint2*)&sA[r * KP + kq * 4] = make_uint2(lo, hi);
    }
  }

  const int w = t >> 6, lane = t & 63;
  const int c15 = lane & 15, q = lane >> 4;

  // B frags for both weight matrices: wave w owns n-tiles {2w, 2w+1}
  short8 bfr0[4][2], bfr1[4][2];
  #pragma unroll
  for (int kc = 0; kc < 4; ++kc)
    #pragma unroll
    for (int nt = 0; nt < 2; ++nt) {
      const int n = (w * 2 + nt) * 16 + c15;
      bfr0[kc][nt] = *(const short8*)&wt[n * 128 + kc * 32 + q * 8];
      bfr1[kc][nt] = *(const short8*)&wt[16384 + n * 128 + kc * 32 + q * 8];
    }
  __syncthreads();

  floatx4 acc0[2][2], acc1[2][2];
  #pragma unroll
  for (int mt = 0; mt < 2; ++mt)
    #pragma unroll
    for (int nt = 0; nt < 2; ++nt) {
      acc0[mt][nt] = (floatx4){0.f, 0.f, 0.f, 0.f};
      acc1[mt][nt] = (floatx4){0.f, 0.f, 0.f, 0.f};
    }
  #pragma unroll
  for (int kc = 0; kc < 4; ++kc)
    #pragma unroll
    for (int mt = 0; mt < 2; ++mt) {
      const short8 afr = *(const short8*)&sA[(mt * 16 + c15) * KP + kc * 32 + q * 8];
      acc0[mt][0] = __builtin_amdgcn_mfma_f32_16x16x32_bf16(afr, bfr0[kc][0], acc0[mt][0], 0, 0, 0);
      acc0[mt][1] = __builtin_amdgcn_mfma_f32_16x16x32_bf16(afr, bfr0[kc][1], acc0[mt][1], 0, 0, 0);
      acc1[mt][0] = __builtin_amdgcn_mfma_f32_16x16x32_bf16(afr, bfr1[kc][0], acc1[mt][0], 0, 0, 0);
      acc1[mt][1] = __builtin_amdgcn_mfma_f32_16x16x32_bf16(afr, bfr1[kc][1], acc1[mt][1], 0, 0, 0);
    }

  const int orow = t >> 3, seg = t & 7;
  const int grow = row0 + orow;

  // ---- pass 0: xh + alpha from acc0 ----
  #pragma unroll
  for (int mt = 0; mt < 2; ++mt)
    #pragma unroll
    for (int nt = 0; nt < 2; ++nt) {
      const int col = (w * 2 + nt) * 16 + c15;
      #pragma unroll
      for (int r = 0; r < 4; ++r)
        sD[(mt * 16 + q * 4 + r) * 132 + col] = acc0[mt][nt][r];
    }
  __syncthreads();
  {
    #pragma unroll
    for (int i = 0; i < 2; ++i) {     // 8 cols per iter
      const float4 v0 = *(const float4*)&sD[orow * 132 + seg * 16 + i * 8];
      const float4 v1 = *(const float4*)&sD[orow * 132 + seg * 16 + i * 8 + 4];
      uint4 u;
      u.x = (unsigned)f2bf(v0.x) | ((unsigned)f2bf(v0.y) << 16);
      u.y = (unsigned)f2bf(v0.z) | ((unsigned)f2bf(v0.w) << 16);
      u.z = (unsigned)f2bf(v1.x) | ((unsigned)f2bf(v1.y) << 16);
      u.w = (unsigned)f2bf(v1.z) | ((unsigned)f2bf(v1.w) << 16);
      *(uint4*)&xh[(long)grow * 128 + seg * 16 + i * 8] = u;
    }
    // fused alpha epilogue: thread = (node orow, head seg); one 16-dot each.
    const int h = seg;
    float sl = 0.f, sr = 0.f;
    #pragma unroll
    for (int c4 = 0; c4 < 4; ++c4) {
      const float4 xv = *(const float4*)&sD[orow * 132 + h * 16 + c4 * 4];
      const float4 lv = *(const float4*)&attl[h * 16 + c4 * 4];
      const float4 rv = *(const float4*)&attr[h * 16 + c4 * 4];
      sl += xv.x * lv.x + xv.y * lv.y + xv.z * lv.z + xv.w * lv.w;
      sr += xv.x * rv.x + xv.y * rv.y + xv.z * rv.z + xv.w * rv.w;
    }
    al[(long)grow * 8 + h] = sl;
    ar[(long)grow * 8 + h] = sr;
  }
  __syncthreads();

  // ---- pass 1: outp from acc1 ----
  #pragma unroll
  for (int mt = 0; mt < 2; ++mt)
    #pragma unroll
    for (int nt = 0; nt < 2; ++nt) {
      const int col = (w * 2 + nt) * 16 + c15;
      #pragma unroll
      for (int r = 0; r < 4; ++r)
        sD[(mt * 16 + q * 4 + r) * 132 + col] = acc1[mt][nt][r];
    }
  __syncthreads();
  #pragma unroll
  for (int i = 0; i < 4; ++i) {
    const float4 v = *(const float4*)&sD[orow * 132 + seg * 16 + i * 4];
    *(float4*)&outp[(long)grow * 128 + seg * 16 + i * 4] = v;
  }
}

// Tile-transpose cnt2 [512][2500] -> cnt2T [2500][512] so k_edgeagg reads a
// CONTIGUOUS 2-KB row instead of 512 strided 64-B lines (~82 MB -> 5 MB).
__global__ __launch_bounds__(256) void k_tr(
    const int* __restrict__ cnt2, int* __restrict__ cnt2T)
{
  __shared__ int tile[32][33];
  const int b0 = blockIdx.x * 32, c0 = blockIdx.y * 32;
  const int tx = threadIdx.x & 31, ty = threadIdx.x >> 5;   // 8 rows/pass
  #pragma unroll
  for (int j = 0; j < 4; ++j) {
    const int c = c0 + ty + j * 8;
    const int b = b0 + tx;
    tile[ty + j * 8][tx] = (b < NBUCK) ? cnt2[c * NBUCK + b] : 0;
  }
  __syncthreads();
  #pragma unroll
  for (int j = 0; j < 4; ++j) {
    const int b = b0 + ty + j * 8;
    if (b < NBUCK) cnt2T[b * NCH + c0 + tx] = tile[tx][ty + j * 8];
  }
}

// FUSED edge+aggregate: one 256-thread block per 16-node bucket (2500 blocks,
// 4 waves, ~19.7 KB LDS -> 8 blocks/CU). Single global sweep + LDS sort:
//  scnt: CONTIGUOUS read from cnt2T (2 KB/block — the round-12 fix).
//  sweep (once): coalesced 16-KB slot-window read; valid slots appended raw
//    to sE (one LDS cursor) + 16-bin count.
//  scan: lanes 0-15 shuffle scan of bins.
//  sort (LDS-local): read sE, exp(logits) (al gathered L2-hot, ar in LDS),
//    counting-sort into sPf (fp32 — no bf16 pack/unpack) / sS.
//  phase 4: sorted per-node register aggregation with 4-edge ILP
//    (round-8-proven; NOT round-10's serial unsorted scan).
// pexp: no max subtraction (logits bounded ~|4|, softmax shift-invariant —
// validated in earlier rounds).
__global__ __launch_bounds__(256, 8) void k_edgeagg(
    const int* __restrict__ cnt2T, const uint2* __restrict__ einfo,
    const int* __restrict__ ovfn, const uint4* __restrict__ ovf,
    const float* __restrict__ al, const float* __restrict__ ar,
    const unsigned short* __restrict__ xh, float* __restrict__ outp)
{
  __shared__ uint2 sE[MAXB];               //  3,072 B (raw slots, unsorted)
  __shared__ float sPf[MAXB * 8];          // 12,288 B (sorted pexp, fp32)
  __shared__ int sS[MAXB];                 //  1,536 B (sorted src ids)
  __shared__ float sAr[128];               //    512 B (16 nodes x 8 heads)
  __shared__ int scnt[NCH];                //  2,048 B (clamped counts)
  __shared__ int bcnt[16], bbase[16], bpos[16], nE;
  const int b = blockIdx.x;
  const int t = threadIdx.x;
  if (t < 16) bcnt[t] = 0;
  if (t == 16) nE = 0;
  if (t < 128) sAr[t] = ar[(long)(b << 4) * 8 + t];
  for (int i = t; i < NCH; i += 256)
    scnt[i] = min(cnt2T[b * NCH + i], CAP);   // contiguous 2-KB read
  __syncthreads();

  const long base = (long)b * SLOTS_B;

  // single global sweep: raw append + bin count
  for (int i = t; i < SLOTS_B; i += 256) {
    const int c = i >> 2, r = i & 3;
    if (r < scnt[c]) {
      const uint2 m = einfo[base + i];
      const int k = atomicAdd(&nE, 1);     // LDS atomic only
      if (k < MAXB) {
        sE[k] = m;
        atomicAdd(&bcnt[m.x & 15], 1);
      }
    }
  }
  const int no = *ovfn;                    // ~210 chip-wide, list L2-hot
  for (int i = t; i < no; i += 256) {
    const uint4 o = ovf[i];
    if ((int)o.x == b) {
      const int k = atomicAdd(&nE, 1);
      if (k < MAXB) {
        sE[k] = make_uint2((o.z << 4) | o.y, o.w);
        atomicAdd(&bcnt[o.y], 1);
      }
    }
  }
  __syncthreads();
  const int nEv = min(nE, MAXB);

  if (t < 16) {            // scan of 16 bins (lanes 0-15, wave 0)
    const int v = bcnt[t];
    int incl = v;
    #pragma unroll
    for (int off = 1; off < 16; off <<= 1) {
      const int n = __shfl_up(incl, off, 16);
      if (t >= off) incl += n;
    }
    bbase[t] = incl - v;
    bpos[t] = 0;
  }
  __syncthreads();

  // LDS-local sort pass: exp + counting sort into sPf/sS (fp32, no packing)
  for (int i = t; i < nEv; i += 256) {
    const uint2 m = sE[i];
    const int dl = m.x & 15;
    const int s = (int)(m.x >> 4);
    const float w = __uint_as_float(m.y);
    const float4 l0 = *(const float4*)&al[(long)s * 8];
    const float4 l1 = *(const float4*)&al[(long)s * 8 + 4];
    const float* arr = &sAr[dl * 8];
    float lv[8] = {l0.x + arr[0], l0.y + arr[1], l0.z + arr[2], l0.w + arr[3],
                   l1.x + arr[4], l1.y + arr[5], l1.z + arr[6], l1.w + arr[7]};
    #pragma unroll
    for (int h = 0; h < 8; ++h) {
      float a = w * lv[h];
      a = (a >= 0.f) ? a : 0.2f * a;   // leaky_relu(0.2)
      lv[h] = __expf(a);
    }
    const int r = atomicAdd(&bpos[dl], 1);   // LDS atomic only
    const int qq = bbase[dl] + r;
    sS[qq] = s;
    *(float4*)&sPf[qq * 8]     = make_float4(lv[0], lv[1], lv[2], lv[3]);
    *(float4*)&sPf[qq * 8 + 4] = make_float4(lv[4], lv[5], lv[6], lv[7]);
  }
  __syncthreads();

  // phase 4: sorted aggregation, 4-edge ILP. wave wv owns nodes wv*4..wv*4+3.
  const int wv = t >> 6, lane = t & 63;
  const int h = lane >> 3;
  const int co = lane * 2;
  #pragma unroll
  for (int j = 0; j < 4; ++j) {
    const int dl = wv * 4 + j;
    const int start = bbase[dl];
    const int end = start + bcnt[dl];
    if (end <= start) continue;   // out already holds residual; elu(0)=0

    float2 a0 = {0.f, 0.f}, a1 = {0.f, 0.f}, a2 = {0.f, 0.f}, a3 = {0.f, 0.f};
    float s0s = 0.f, s1s = 0.f, s2s = 0.f, s3s = 0.f;
    int p = start;
    for (; p + 4 <= end; p += 4) {
      const int s0 = sS[p + 0], s1 = sS[p + 1];
      const int s2 = sS[p + 2], s3 = sS[p + 3];
      const float e0v = sPf[(p + 0) * 8 + h];
      const float e1v = sPf[(p + 1) * 8 + h];
      const float e2v = sPf[(p + 2) * 8 + h];
      const float e3v = sPf[(p + 3) * 8 + h];
      const unsigned v0 = *(const unsigned*)&xh[(long)s0 * 128 + co];
      const unsigned v1 = *(const unsigned*)&xh[(long)s1 * 128 + co];
      const unsigned v2 = *(const unsigned*)&xh[(long)s2 * 128 + co];
      const unsigned v3 = *(const unsigned*)&xh[(long)s3 * 128 + co];
      a0.x = fmaf(bflo(v0), e0v, a0.x); a0.y = fmaf(bfhi(v0), e0v, a0.y); s0s += e0v;
      a1.x = fmaf(bflo(v1), e1v, a1.x); a1.y = fmaf(bfhi(v1), e1v, a1.y); s1s += e1v;
      a2.x = fmaf(bflo(v2), e2v, a2.x); a2.y = fmaf(bfhi(v2), e2v, a2.y); s2s += e2v;
      a3.x = fmaf(bflo(v3), e3v, a3.x); a3.y = fmaf(bfhi(v3), e3v, a3.y); s3s += e3v;
    }
    for (; p < end; ++p) {
      const int s = sS[p];
      const float ev = sPf[p * 8 + h];
      const unsigned v = *(const unsigned*)&xh[(long)s * 128 + co];
      a0.x = fmaf(bflo(v), ev, a0.x);
      a0.y = fmaf(bfhi(v), ev, a0.y);
      s0s += ev;
    }
    const float rs = 1.0f / ((s0s + s1s) + (s2s + s3s));
    const float ax = ((a0.x + a1.x) + (a2.x + a3.x)) * rs;
    const float ay = ((a0.y + a1.y) + (a2.y + a3.y)) * rs;

    const long dnode = (long)(b << 4) + dl;
    float2 o = *(float2*)&outp[dnode * 128 + co];
    o.x += (ax > 0.f) ? ax : expm1f(ax);
    o.y += (ay > 0.f) ? ay : expm1f(ay);
    *(float2*)&outp[dnode * 128 + co] = o;
  }
}

extern "C" void kernel_launch(void* const* d_in, const int* in_sizes, int n_in,
                              void* d_out, int out_size, void* d_ws, size_t ws_size,
                              hipStream_t stream) {
  const float* feat = (const float*)d_in[0];
  const int*   eidx = (const int*)d_in[1];
  const float* ew   = (const float*)d_in[2];
  const float* Wlin = (const float*)d_in[3];
  const float* attl = (const float*)d_in[4];
  const float* attr = (const float*)d_in[5];
  const float* Wres = (const float*)d_in[6];
  float* outp = (float*)d_out;

  float* ws = (float*)d_ws;
  unsigned short* xh = (unsigned short*)ws;
  float* al   = ws + 5120000;
  float* ar   = ws + 5440000;
  uint2* einfo = (uint2*)(ws + 6000000);   // NBUCK*SLOTS_B uint2 (40.9 MB)
  int*   cnt2 = (int*)(ws + 16300000);
  int*   ovfn = (int*)(ws + 17600000);
  uint4* ovf  = (uint4*)(ws + 17600064);
  int*   cnt2T = (int*)(ws + 17700000);    // [2500][512] ints
  unsigned short* wt = (unsigned short*)(ws + 19000000);

  const int* src = eidx;
  const int* dst = eidx + N_EDGES;

  dim3 pgrid(128, 2);
  k_prep<<<pgrid, 128, 0, stream>>>(Wlin, Wres, wt, ovfn);
  dim3 ggrid(NBG, 2);   // y=0 dual GEMM + alpha, y=1 count + direct scatter
  k_gemm<<<ggrid, 256, 0, stream>>>(feat, wt, xh, outp, attl, attr, al, ar,
                                    src, dst, ew, einfo, cnt2, ovfn, ovf);
  dim3 tgrid((NBUCK + 31) / 32, NCH / 32);
  k_tr<<<tgrid, 256, 0, stream>>>(cnt2, cnt2T);
  k_edgeagg<<<NBUCK, 256, 0, stream>>>(cnt2T, einfo, ovfn, ovf, al, ar,
                                       xh, outp);
}

// Round 14
// 150.334 us; speedup vs baseline: 1.4372x; 1.0731x over previous
//
#include <hip/hip_runtime.h>
#include <math.h>

#define N_NODES 40000
#define N_EDGES 640000
#define D 128
#define H 8
#define C 16
#define NBG 1250     // 40000/32 exactly
#define KP 136       // sA k-stride (bf16 elems)
#define NBUCK 1250   // 32-node buckets: bucket = dst >> 5 (40000 = 1250*32)
#define NCH 512      // chunks (1250 edges each) — 512 count blocks, 2/CU
#define ECH 1250     // edges per chunk (512*1250 = 640000)
#define CAP 8        // per-(bucket,chunk) slots = exactly one 64-B line;
                     // lambda=1, E[overflow] ~1 edge chip-wide
#define SLOTS_B (NCH * CAP)   // 4096 slots (32 KB) per bucket
#define MAXB 768     // bucket-size bound (mean 512, sigma ~23; 11-sigma)
#define OVCAP 4096   // global overflow list capacity

typedef __attribute__((ext_vector_type(8))) short short8;   // 8 bf16 (4 VGPRs)
typedef __attribute__((ext_vector_type(4))) float floatx4;  // MFMA C/D

// ws layout (float offsets):
//  xh    : 0          .. 2,560,000   (N*128 bf16 stored as ushort)
//  al    : 5,120,000  .. 5,440,000   (N*8)
//  ar    : 5,440,000  .. 5,760,000   (N*8)
//  einfo : 6,000,000  .. 16,240,000  (NBUCK*SLOTS_B uint2 fixed 64-B cells;
//                                     einfo[(b*512+c)*8+r]={(src<<5)|dl, ew})
//  cnt2  : 16,300,000 .. 16,940,000  ([512][1250] ints, chunk-major counts)
//  ovfn  : 17,600,000 (1 int)  ovf: 17,600,064 .. +4*OVCAP (uint4 entries)
//  cnt2T : 17,700,000 .. 18,340,000  ([1250][512] ints, bucket-major counts)
//  wt    : 19,000,000 .. +16,384     (2x 128x128 bf16 transposed weights)

__device__ __forceinline__ unsigned short f2bf(float f) {
  const unsigned u = __float_as_uint(f);
  return (unsigned short)((u + 0x7FFFu + ((u >> 16) & 1u)) >> 16);  // RNE
}
__device__ __forceinline__ float bflo(unsigned p) {
  return __uint_as_float(p << 16);
}
__device__ __forceinline__ float bfhi(unsigned p) {
  return __uint_as_float(p & 0xFFFF0000u);
}
__device__ __forceinline__ float bf2f(unsigned short u) {
  return __uint_as_float((unsigned)u << 16);
}

// Pre-transpose W (fp32 [k][n]) -> wt (bf16 [g][n][k]). Also zeroes the
// overflow counter (runs before k_gemm in-stream).
__global__ void k_prep(const float* __restrict__ Wlin,
                       const float* __restrict__ Wres,
                       unsigned short* __restrict__ wt, int* __restrict__ ovfn)
{
  const int n = blockIdx.x, k = threadIdx.x, g = blockIdx.y;
  if (n == 0 && g == 0 && k == 0) *ovfn = 0;
  const float* W = g ? Wres : Wlin;
  wt[((g * 128 + n) * 128) + k] = f2bf(W[(long)k * 128 + n]);
}

// MFMA bf16 GEMM, 32-row blocks, BOTH weight matrices per block.
// blockIdx.y==0: xh=bf16(feat@Wlin) + fused alpha epilogue, outp=feat@Wres.
// blockIdx.y==1: count pass (512 blocks x 1250 edges — proven parallelism)
//   scattering einfo into fixed ONE-LINE (64-B) cells:
//   slot=(b*512+c)*8 + r (r = LDS rank). Rare r>=8 -> global overflow list.
__global__ __launch_bounds__(256, 4) void k_gemm(
    const float* __restrict__ feat, const unsigned short* __restrict__ wt,
    unsigned short* __restrict__ xh, float* __restrict__ outp,
    const float* __restrict__ attl, const float* __restrict__ attr,
    float* __restrict__ al, float* __restrict__ ar,
    const int* __restrict__ src, const int* __restrict__ dst,
    const float* __restrict__ ew, uint2* __restrict__ einfo,
    int* __restrict__ cnt2, int* __restrict__ ovfn, uint4* __restrict__ ovf)
{
  __shared__ short sA[32 * KP];     // 8,704 B
  __shared__ float sD[32 * 132];    // 16,896 B
  const int t = threadIdx.x;

  if (blockIdx.y == 1) {            // fused count + direct-scatter pass
    if (blockIdx.x >= NCH) return;
    int* lcnt = (int*)sD;           // 5,000 B (1250 bins)
    for (int i = t; i < NBUCK; i += 256) lcnt[i] = 0;
    __syncthreads();
    const int c = blockIdx.x;
    const int e0 = c * ECH;
    for (int e = e0 + t; e < e0 + ECH; e += 256) {
      const int d = dst[e];
      const int b = d >> 5, dl = d & 31;
      const int r = atomicAdd(&lcnt[b], 1);   // LDS atomic only
      const unsigned pay = ((unsigned)src[e] << 5) | (unsigned)dl;
      const unsigned wbits = __float_as_uint(ew[e]);
      if (r < CAP) {
        einfo[((long)b * NCH + c) * CAP + r] = make_uint2(pay, wbits);
      } else {                                 // ~1 expected edge total
        const int oi = atomicAdd(ovfn, 1);
        if (oi < OVCAP)
          ovf[oi] = make_uint4((unsigned)b, (unsigned)dl,
                               (unsigned)src[e], wbits);
      }
    }
    __syncthreads();
    for (int i = t; i < NBUCK; i += 256) cnt2[c * NBUCK + i] = lcnt[i];
    return;
  }

  const int row0 = blockIdx.x * 32;

  // stage A: 32 rows x 128 k, fp32 -> bf16 (coalesced float4 reads)
  {
    const int kq = t & 31;            // k = kq*4
    const int rb = (t >> 5) * 4;      // 4 rows per thread
    #pragma unroll
    for (int i = 0; i < 4; ++i) {
      const int r = rb + i;
      const float4 f = *(const float4*)&feat[(long)(row0 + r) * 128 + kq * 4];
      const unsigned lo = (unsigned)f2bf(f.x) | ((unsigned)f2bf(f.y) << 16);
      const unsigned hi = (unsigned)f2bf(f.z) | ((unsigned)f2bf(f.w) << 16);
      *(uint2*)&sA[r * KP + kq * 4] = make_uint2(lo, hi);
    }
  }

  const int w = t >> 6, lane = t & 63;
  const int c15 = lane & 15, q = lane >> 4;

  // B frags for both weight matrices: wave w owns n-tiles {2w, 2w+1}
  short8 bfr0[4][2], bfr1[4][2];
  #pragma unroll
  for (int kc = 0; kc < 4; ++kc)
    #pragma unroll
    for (int nt = 0; nt < 2; ++nt) {
      const int n = (w * 2 + nt) * 16 + c15;
      bfr0[kc][nt] = *(const short8*)&wt[n * 128 + kc * 32 + q * 8];
      bfr1[kc][nt] = *(const short8*)&wt[16384 + n * 128 + kc * 32 + q * 8];
    }
  __syncthreads();

  floatx4 acc0[2][2], acc1[2][2];
  #pragma unroll
  for (int mt = 0; mt < 2; ++mt)
    #pragma unroll
    for (int nt = 0; nt < 2; ++nt) {
      acc0[mt][nt] = (floatx4){0.f, 0.f, 0.f, 0.f};
      acc1[mt][nt] = (floatx4){0.f, 0.f, 0.f, 0.f};
    }
  #pragma unroll
  for (int kc = 0; kc < 4; ++kc)
    #pragma unroll
    for (int mt = 0; mt < 2; ++mt) {
      const short8 afr = *(const short8*)&sA[(mt * 16 + c15) * KP + kc * 32 + q * 8];
      acc0[mt][0] = __builtin_amdgcn_mfma_f32_16x16x32_bf16(afr, bfr0[kc][0], acc0[mt][0], 0, 0, 0);
      acc0[mt][1] = __builtin_amdgcn_mfma_f32_16x16x32_bf16(afr, bfr0[kc][1], acc0[mt][1], 0, 0, 0);
      acc1[mt][0] = __builtin_amdgcn_mfma_f32_16x16x32_bf16(afr, bfr1[kc][0], acc1[mt][0], 0, 0, 0);
      acc1[mt][1] = __builtin_amdgcn_mfma_f32_16x16x32_bf16(afr, bfr1[kc][1], acc1[mt][1], 0, 0, 0);
    }

  const int orow = t >> 3, seg = t & 7;
  const int grow = row0 + orow;

  // ---- pass 0: xh + alpha from acc0 ----
  #pragma unroll
  for (int mt = 0; mt < 2; ++mt)
    #pragma unroll
    for (int nt = 0; nt < 2; ++nt) {
      const int col = (w * 2 + nt) * 16 + c15;
      #pragma unroll
      for (int r = 0; r < 4; ++r)
        sD[(mt * 16 + q * 4 + r) * 132 + col] = acc0[mt][nt][r];
    }
  __syncthreads();
  {
    #pragma unroll
    for (int i = 0; i < 2; ++i) {     // 8 cols per iter
      const float4 v0 = *(const float4*)&sD[orow * 132 + seg * 16 + i * 8];
      const float4 v1 = *(const float4*)&sD[orow * 132 + seg * 16 + i * 8 + 4];
      uint4 u;
      u.x = (unsigned)f2bf(v0.x) | ((unsigned)f2bf(v0.y) << 16);
      u.y = (unsigned)f2bf(v0.z) | ((unsigned)f2bf(v0.w) << 16);
      u.z = (unsigned)f2bf(v1.x) | ((unsigned)f2bf(v1.y) << 16);
      u.w = (unsigned)f2bf(v1.z) | ((unsigned)f2bf(v1.w) << 16);
      *(uint4*)&xh[(long)grow * 128 + seg * 16 + i * 8] = u;
    }
    // fused alpha epilogue: thread = (node orow, head seg); one 16-dot each.
    const int h = seg;
    float sl = 0.f, sr = 0.f;
    #pragma unroll
    for (int c4 = 0; c4 < 4; ++c4) {
      const float4 xv = *(const float4*)&sD[orow * 132 + h * 16 + c4 * 4];
      const float4 lv = *(const float4*)&attl[h * 16 + c4 * 4];
      const float4 rv = *(const float4*)&attr[h * 16 + c4 * 4];
      sl += xv.x * lv.x + xv.y * lv.y + xv.z * lv.z + xv.w * lv.w;
      sr += xv.x * rv.x + xv.y * rv.y + xv.z * rv.z + xv.w * rv.w;
    }
    al[(long)grow * 8 + h] = sl;
    ar[(long)grow * 8 + h] = sr;
  }
  __syncthreads();

  // ---- pass 1: outp from acc1 ----
  #pragma unroll
  for (int mt = 0; mt < 2; ++mt)
    #pragma unroll
    for (int nt = 0; nt < 2; ++nt) {
      const int col = (w * 2 + nt) * 16 + c15;
      #pragma unroll
      for (int r = 0; r < 4; ++r)
        sD[(mt * 16 + q * 4 + r) * 132 + col] = acc1[mt][nt][r];
    }
  __syncthreads();
  #pragma unroll
  for (int i = 0; i < 4; ++i) {
    const float4 v = *(const float4*)&sD[orow * 132 + seg * 16 + i * 4];
    *(float4*)&outp[(long)grow * 128 + seg * 16 + i * 4] = v;
  }
}

// Tile-transpose cnt2 [512][1250] -> cnt2T [1250][512] so k_edgeagg reads a
// CONTIGUOUS 2-KB row instead of 512 strided lines (round-12-proven, -19 MB).
__global__ __launch_bounds__(256) void k_tr(
    const int* __restrict__ cnt2, int* __restrict__ cnt2T)
{
  __shared__ int tile[32][33];
  const int b0 = blockIdx.x * 32, c0 = blockIdx.y * 32;
  const int tx = threadIdx.x & 31, ty = threadIdx.x >> 5;   // 8 rows/pass
  #pragma unroll
  for (int j = 0; j < 4; ++j) {
    const int c = c0 + ty + j * 8;
    const int b = b0 + tx;
    tile[ty + j * 8][tx] = (b < NBUCK) ? cnt2[c * NBUCK + b] : 0;
  }
  __syncthreads();
  #pragma unroll
  for (int j = 0; j < 4; ++j) {
    const int b = b0 + ty + j * 8;
    if (b < NBUCK) cnt2T[b * NCH + c0 + tx] = tile[tx][ty + j * 8];
  }
}

// FUSED edge+aggregate: one 256-thread block per 32-node bucket (1250 blocks,
// 4 waves, ~23.5 KB LDS -> 6 blocks/CU; 1250 < 6*256 => SINGLE grid round).
//  scnt: contiguous 2-KB read from cnt2T.
//  sweep (once): coalesced read of the 32-KB slot window (64-B line cells,
//    lambda=1 => ~26 MB chip-total); valid slots appended raw to sE + 32-bin
//    count.
//  scan: lanes 0-31 shuffle scan of bins.
//  sort (LDS-local): read sE, exp(logits) (al gathered L2-hot, ar in LDS),
//    counting-sort into sP (bf16) / sS (ushort).
//  phase 4: sorted per-node register aggregation with 4-edge ILP
//    (round-8-proven); wave wv owns 8 nodes.
// pexp: no max subtraction (logits bounded ~|4|, softmax shift-invariant —
// validated in earlier rounds).
__global__ __launch_bounds__(256, 6) void k_edgeagg(
    const int* __restrict__ cnt2T, const uint2* __restrict__ einfo,
    const int* __restrict__ ovfn, const uint4* __restrict__ ovf,
    const float* __restrict__ al, const float* __restrict__ ar,
    const unsigned short* __restrict__ xh, float* __restrict__ outp)
{
  __shared__ uint2 sE[MAXB];                //  6,144 B (raw slots, unsorted)
  __shared__ unsigned short sP[MAXB * 8];   // 12,288 B (sorted pexp, bf16)
  __shared__ unsigned short sS[MAXB];       //  1,536 B (sorted src ids, u16)
  __shared__ float sAr[256];                //  1,024 B (32 nodes x 8 heads)
  __shared__ int scnt[NCH];                 //  2,048 B (clamped counts)
  __shared__ int bcnt[32], bbase[32], bpos[32], nE;
  const int b = blockIdx.x;
  const int t = threadIdx.x;
  if (t < 32) bcnt[t] = 0;
  if (t == 32) nE = 0;
  if (t < 256) sAr[t] = ar[(long)(b << 5) * 8 + t];
  for (int i = t; i < NCH; i += 256)
    scnt[i] = min(cnt2T[b * NCH + i], CAP);   // contiguous 2-KB read
  __syncthreads();

  const long base = (long)b * SLOTS_B;

  // single global sweep: raw append + bin count
  for (int i = t; i < SLOTS_B; i += 256) {
    const int c = i >> 3, r = i & 7;
    if (r < scnt[c]) {
      const uint2 m = einfo[base + i];
      const int k = atomicAdd(&nE, 1);     // LDS atomic only
      if (k < MAXB) {
        sE[k] = m;
        atomicAdd(&bcnt[m.x & 31], 1);
      }
    }
  }
  const int no = *ovfn;                    // ~1 chip-wide, list L2-hot
  for (int i = t; i < no; i += 256) {
    const uint4 o = ovf[i];
    if ((int)o.x == b) {
      const int k = atomicAdd(&nE, 1);
      if (k < MAXB) {
        sE[k] = make_uint2((o.z << 5) | o.y, o.w);
        atomicAdd(&bcnt[o.y], 1);
      }
    }
  }
  __syncthreads();
  const int nEv = min(nE, MAXB);

  if (t < 32) {            // scan of 32 bins (lanes 0-31, wave 0)
    const int v = bcnt[t];
    int incl = v;
    #pragma unroll
    for (int off = 1; off < 32; off <<= 1) {
      const int n = __shfl_up(incl, off, 32);
      if (t >= off) incl += n;
    }
    bbase[t] = incl - v;
    bpos[t] = 0;
  }
  __syncthreads();

  // LDS-local sort pass: exp + counting sort into sP/sS
  for (int i = t; i < nEv; i += 256) {
    const uint2 m = sE[i];
    const int dl = m.x & 31;
    const int s = (int)(m.x >> 5);
    const float w = __uint_as_float(m.y);
    const float4 l0 = *(const float4*)&al[(long)s * 8];
    const float4 l1 = *(const float4*)&al[(long)s * 8 + 4];
    const float* arr = &sAr[dl * 8];
    float lv[8] = {l0.x + arr[0], l0.y + arr[1], l0.z + arr[2], l0.w + arr[3],
                   l1.x + arr[4], l1.y + arr[5], l1.z + arr[6], l1.w + arr[7]};
    #pragma unroll
    for (int h = 0; h < 8; ++h) {
      float a = w * lv[h];
      a = (a >= 0.f) ? a : 0.2f * a;   // leaky_relu(0.2)
      lv[h] = __expf(a);
    }
    const int r = atomicAdd(&bpos[dl], 1);   // LDS atomic only
    const int qq = bbase[dl] + r;
    sS[qq] = (unsigned short)s;
    uint4 u;
    u.x = (unsigned)f2bf(lv[0]) | ((unsigned)f2bf(lv[1]) << 16);
    u.y = (unsigned)f2bf(lv[2]) | ((unsigned)f2bf(lv[3]) << 16);
    u.z = (unsigned)f2bf(lv[4]) | ((unsigned)f2bf(lv[5]) << 16);
    u.w = (unsigned)f2bf(lv[6]) | ((unsigned)f2bf(lv[7]) << 16);
    *(uint4*)&sP[qq * 8] = u;
  }
  __syncthreads();

  // phase 4: sorted aggregation, 4-edge ILP. wave wv owns nodes wv*8..wv*8+7.
  const int wv = t >> 6, lane = t & 63;
  const int h = lane >> 3;
  const int co = lane * 2;
  #pragma unroll
  for (int j = 0; j < 8; ++j) {
    const int dl = wv * 8 + j;
    const int start = bbase[dl];
    const int end = start + bcnt[dl];
    if (end <= start) continue;   // out already holds residual; elu(0)=0

    float2 a0 = {0.f, 0.f}, a1 = {0.f, 0.f}, a2 = {0.f, 0.f}, a3 = {0.f, 0.f};
    float s0s = 0.f, s1s = 0.f, s2s = 0.f, s3s = 0.f;
    int p = start;
    for (; p + 4 <= end; p += 4) {
      const int s0 = sS[p + 0], s1 = sS[p + 1];
      const int s2 = sS[p + 2], s3 = sS[p + 3];
      const float e0v = bf2f(sP[(p + 0) * 8 + h]);
      const float e1v = bf2f(sP[(p + 1) * 8 + h]);
      const float e2v = bf2f(sP[(p + 2) * 8 + h]);
      const float e3v = bf2f(sP[(p + 3) * 8 + h]);
      const unsigned v0 = *(const unsigned*)&xh[(long)s0 * 128 + co];
      const unsigned v1 = *(const unsigned*)&xh[(long)s1 * 128 + co];
      const unsigned v2 = *(const unsigned*)&xh[(long)s2 * 128 + co];
      const unsigned v3 = *(const unsigned*)&xh[(long)s3 * 128 + co];
      a0.x = fmaf(bflo(v0), e0v, a0.x); a0.y = fmaf(bfhi(v0), e0v, a0.y); s0s += e0v;
      a1.x = fmaf(bflo(v1), e1v, a1.x); a1.y = fmaf(bfhi(v1), e1v, a1.y); s1s += e1v;
      a2.x = fmaf(bflo(v2), e2v, a2.x); a2.y = fmaf(bfhi(v2), e2v, a2.y); s2s += e2v;
      a3.x = fmaf(bflo(v3), e3v, a3.x); a3.y = fmaf(bfhi(v3), e3v, a3.y); s3s += e3v;
    }
    for (; p < end; ++p) {
      const int s = sS[p];
      const float ev = bf2f(sP[p * 8 + h]);
      const unsigned v = *(const unsigned*)&xh[(long)s * 128 + co];
      a0.x = fmaf(bflo(v), ev, a0.x);
      a0.y = fmaf(bfhi(v), ev, a0.y);
      s0s += ev;
    }
    const float rs = 1.0f / ((s0s + s1s) + (s2s + s3s));
    const float ax = ((a0.x + a1.x) + (a2.x + a3.x)) * rs;
    const float ay = ((a0.y + a1.y) + (a2.y + a3.y)) * rs;

    const long dnode = (long)(b << 5) + dl;
    float2 o = *(float2*)&outp[dnode * 128 + co];
    o.x += (ax > 0.f) ? ax : expm1f(ax);
    o.y += (ay > 0.f) ? ay : expm1f(ay);
    *(float2*)&outp[dnode * 128 + co] = o;
  }
}

extern "C" void kernel_launch(void* const* d_in, const int* in_sizes, int n_in,
                              void* d_out, int out_size, void* d_ws, size_t ws_size,
                              hipStream_t stream) {
  const float* feat = (const float*)d_in[0];
  const int*   eidx = (const int*)d_in[1];
  const float* ew   = (const float*)d_in[2];
  const float* Wlin = (const float*)d_in[3];
  const float* attl = (const float*)d_in[4];
  const float* attr = (const float*)d_in[5];
  const float* Wres = (const float*)d_in[6];
  float* outp = (float*)d_out;

  float* ws = (float*)d_ws;
  unsigned short* xh = (unsigned short*)ws;
  float* al   = ws + 5120000;
  float* ar   = ws + 5440000;
  uint2* einfo = (uint2*)(ws + 6000000);   // NBUCK*SLOTS_B uint2 (40.9 MB)
  int*   cnt2 = (int*)(ws + 16300000);
  int*   ovfn = (int*)(ws + 17600000);
  uint4* ovf  = (uint4*)(ws + 17600064);
  int*   cnt2T = (int*)(ws + 17700000);    // [1250][512] ints
  unsigned short* wt = (unsigned short*)(ws + 19000000);

  const int* src = eidx;
  const int* dst = eidx + N_EDGES;

  dim3 pgrid(128, 2);
  k_prep<<<pgrid, 128, 0, stream>>>(Wlin, Wres, wt, ovfn);
  dim3 ggrid(NBG, 2);   // y=0 dual GEMM + alpha, y=1 count + direct scatter
  k_gemm<<<ggrid, 256, 0, stream>>>(feat, wt, xh, outp, attl, attr, al, ar,
                                    src, dst, ew, einfo, cnt2, ovfn, ovf);
  dim3 tgrid((NBUCK + 31) / 32, NCH / 32);
  k_tr<<<tgrid, 256, 0, stream>>>(cnt2, cnt2T);
  k_edgeagg<<<NBUCK, 256, 0, stream>>>(cnt2T, einfo, ovfn, ovf, al, ar,
                                       xh, outp);
}